// Round 2
// baseline (992.325 us; speedup 1.0000x reference)
//
#include <hip/hip_runtime.h>

// TemporalGCN: 2-layer GCN (gcn_norm with self-loops) + linear head.
// dims: in=128, hid=64, out=16; N=100000 nodes, E=1.6M edges.

constexpr int ID = 128;  // input dim
constexpr int HD = 64;   // hidden dim
constexpr int OD = 16;   // output dim

// ---- degree: count incoming edges (self-loop added later as +1) ----
__global__ void deg_kernel(const int* __restrict__ dst, float* __restrict__ deg, int E) {
    int i = blockIdx.x * blockDim.x + threadIdx.x;
    int n = gridDim.x * blockDim.x;
    for (int e = i; e < E; e += n)
        atomicAdd(&deg[dst[e]], 1.0f);
}

// deg -> D^{-1/2}, in place. deg+1 accounts for the self-loop, always > 0.
__global__ void dinv_kernel(float* __restrict__ deg, int N) {
    int i = blockIdx.x * blockDim.x + threadIdx.x;
    if (i < N) deg[i] = rsqrtf(deg[i] + 1.0f);
}

// ---- GEMM1: t = x @ W1  [N,128]x[128,64]; also a = t * dinv^2 (self-loop init)
__global__ __launch_bounds__(256) void gemm1_kernel(
    const float* __restrict__ x, const float* __restrict__ W,
    const float* __restrict__ dinv, float* __restrict__ t,
    float* __restrict__ a, int N) {
    __shared__ float Ws[ID * HD];   // 32 KB
    __shared__ float xs[8][ID];     // 4 KB
    int tid = threadIdx.x;
    for (int i = tid; i < ID * HD; i += 256) Ws[i] = W[i];
    int base = blockIdx.x * 8;
    for (int i = tid; i < 8 * ID; i += 256) {
        int r = i >> 7, c = i & (ID - 1);
        int row = base + r;
        xs[r][c] = (row < N) ? x[(size_t)row * ID + c] : 0.0f;
    }
    __syncthreads();
    int col = tid & 63;
    int rg  = tid >> 6;  // wave id: 0..3, each wave does 2 rows
    float acc0 = 0.f, acc1 = 0.f;
    #pragma unroll 8
    for (int k = 0; k < ID; ++k) {
        float w = Ws[k * HD + col];
        acc0 += xs[rg * 2][k] * w;
        acc1 += xs[rg * 2 + 1][k] * w;
    }
    int r0 = base + rg * 2, r1 = r0 + 1;
    if (r0 < N) { float di = dinv[r0]; t[(size_t)r0*HD+col] = acc0; a[(size_t)r0*HD+col] = acc0*di*di; }
    if (r1 < N) { float di = dinv[r1]; t[(size_t)r1*HD+col] = acc1; a[(size_t)r1*HD+col] = acc1*di*di; }
}

// ---- edge scatter: a[dst] += t[src] * dinv[src]*dinv[dst], one wave per edge
__global__ __launch_bounds__(256) void scatter_kernel(
    const int* __restrict__ src, const int* __restrict__ dst,
    const float* __restrict__ dinv, const float* __restrict__ t,
    float* __restrict__ a, int E) {
    int lane = threadIdx.x & 63;
    int wid  = (blockIdx.x * blockDim.x + threadIdx.x) >> 6;
    int nw   = (gridDim.x * blockDim.x) >> 6;
    for (int e = wid; e < E; e += nw) {
        int s = src[e], d = dst[e];
        float nv = dinv[s] * dinv[d];
        atomicAdd(&a[(size_t)d * HD + lane], t[(size_t)s * HD + lane] * nv);
    }
}

// ---- GEMM2: t2 = relu(a1 + b1) @ W2; a2 = t2 * dinv^2. a2 may alias a1
// (each block reads exactly the rows it later writes, staged through LDS).
__global__ __launch_bounds__(256) void gemm2_kernel(
    const float* __restrict__ ain, const float* __restrict__ W,
    const float* __restrict__ bias, const float* __restrict__ dinv,
    float* __restrict__ t, float* __restrict__ a, int N) {
    __shared__ float Ws[HD * HD];   // 16 KB
    __shared__ float hs[8][HD];     // 2 KB
    int tid = threadIdx.x;
    for (int i = tid; i < HD * HD; i += 256) Ws[i] = W[i];
    int base = blockIdx.x * 8;
    for (int i = tid; i < 8 * HD; i += 256) {
        int r = i >> 6, c = i & 63;
        int row = base + r;
        float v = (row < N) ? ain[(size_t)row * HD + c] + bias[c] : 0.0f;
        hs[r][c] = fmaxf(v, 0.0f);
    }
    __syncthreads();
    int col = tid & 63;
    int rg  = tid >> 6;
    float acc0 = 0.f, acc1 = 0.f;
    #pragma unroll 8
    for (int k = 0; k < HD; ++k) {
        float w = Ws[k * HD + col];
        acc0 += hs[rg * 2][k] * w;
        acc1 += hs[rg * 2 + 1][k] * w;
    }
    int r0 = base + rg * 2, r1 = r0 + 1;
    if (r0 < N) { float di = dinv[r0]; t[(size_t)r0*HD+col] = acc0; a[(size_t)r0*HD+col] = acc0*di*di; }
    if (r1 < N) { float di = dinv[r1]; t[(size_t)r1*HD+col] = acc1; a[(size_t)r1*HD+col] = acc1*di*di; }
}

// ---- head: out = (a2 + b2) @ Wc + bc   [N,64]x[64,16]
__global__ __launch_bounds__(256) void final_kernel(
    const float* __restrict__ ain, const float* __restrict__ b2,
    const float* __restrict__ Wc, const float* __restrict__ bc,
    float* __restrict__ out, int N) {
    __shared__ float Ws[HD * OD];     // 4 KB
    __shared__ float hs[16][HD + 1];  // padded: avoid 4-way bank conflict on hs[r][k]
    int tid = threadIdx.x;
    for (int i = tid; i < HD * OD; i += 256) Ws[i] = Wc[i];
    int base = blockIdx.x * 16;
    for (int i = tid; i < 16 * HD; i += 256) {
        int r = i >> 6, c = i & 63;
        int row = base + r;
        hs[r][c] = (row < N) ? ain[(size_t)row * HD + c] + b2[c] : 0.0f;
    }
    __syncthreads();
    int col = tid & 15, r = tid >> 4;
    int row = base + r;
    if (row < N) {
        float acc = bc[col];
        #pragma unroll
        for (int k = 0; k < HD; ++k)
            acc += hs[r][k] * Ws[k * OD + col];
        out[(size_t)row * OD + col] = acc;
    }
}

extern "C" void kernel_launch(void* const* d_in, const int* in_sizes, int n_in,
                              void* d_out, int out_size, void* d_ws, size_t ws_size,
                              hipStream_t stream) {
    const float* x  = (const float*)d_in[0];
    const int*   ei = (const int*)d_in[1];   // int per harness contract: [2,E] flat
    const float* W1 = (const float*)d_in[2];
    const float* b1 = (const float*)d_in[3];
    const float* W2 = (const float*)d_in[4];
    const float* b2 = (const float*)d_in[5];
    const float* Wc = (const float*)d_in[6];
    const float* bc = (const float*)d_in[7];
    float* out = (float*)d_out;

    int N = in_sizes[0] / ID;   // 100000
    int E = in_sizes[1] / 2;    // 1600000
    const int* src = ei;
    const int* dst = ei + E;

    int Npad = (N + 63) & ~63;
    float* deg  = (float*)d_ws;           // [N]   degree -> dinv (in place)
    float* bufA = deg + Npad;             // [N,64] t1 then t2
    float* bufB = bufA + (size_t)N * HD;  // [N,64] a1 then a2 (in-place reuse)

    // ws is poisoned each call: zero the degree accumulator. bufA/bufB are
    // fully written before being read.
    hipMemsetAsync(deg, 0, (size_t)N * sizeof(float), stream);

    deg_kernel<<<2048, 256, 0, stream>>>(dst, deg, E);
    dinv_kernel<<<(N + 255) / 256, 256, 0, stream>>>(deg, N);

    gemm1_kernel<<<(N + 7) / 8, 256, 0, stream>>>(x, W1, deg, bufA, bufB, N);
    scatter_kernel<<<2048, 256, 0, stream>>>(src, dst, deg, bufA, bufB, E);

    gemm2_kernel<<<(N + 7) / 8, 256, 0, stream>>>(bufB, W2, b1, deg, bufA, bufB, N);
    scatter_kernel<<<2048, 256, 0, stream>>>(src, dst, deg, bufA, bufB, E);

    final_kernel<<<(N + 15) / 16, 256, 0, stream>>>(bufB, b2, Wc, bc, out, N);
}

// Round 3
// 555.372 us; speedup vs baseline: 1.7868x; 1.7868x over previous
//
#include <hip/hip_runtime.h>
#include <hip/hip_fp16.h>

// TemporalGCN: 2-layer GCN (gcn_norm with self-loops) + linear head.
// dims: in=128, hid=64, out=16; N=100000 nodes, E=1.6M edges.
//
// R2 finding: push-scatter with fp32 atomics is atomic-op-rate bound at TCC
// (400MB WRITE_SIZE/scatter = 1 dword-atomic per feature per edge, ~300G/s).
// R3: build CSR (sorted by dst) once per call, then PULL aggregation with
// zero atomics in the hot loop. Message tables in fp16 (halves gather bytes).

constexpr int ID = 128;  // input dim
constexpr int HD = 64;   // hidden dim
constexpr int OD = 16;   // output dim

// ---- histogram of dst (in-degree, excluding self-loop) ----
__global__ void hist_kernel(const int* __restrict__ dst, int* __restrict__ cnt, int E) {
    int i = blockIdx.x * blockDim.x + threadIdx.x;
    int n = gridDim.x * blockDim.x;
    for (int e = i; e < E; e += n)
        atomicAdd(&cnt[dst[e]], 1);
}

// dinv[i] = rsqrt(deg+1)  (+1 = self-loop)
__global__ void dinv_kernel(const int* __restrict__ cnt, float* __restrict__ dinv, int N) {
    int i = blockIdx.x * blockDim.x + threadIdx.x;
    if (i < N) dinv[i] = rsqrtf((float)cnt[i] + 1.0f);
}

// ---- 3-phase exclusive scan of cnt[N] -> off[N+1], cursor[N] ----
// CHUNK = 1024 elements per block (256 threads x 4).
__global__ __launch_bounds__(256) void scanA_kernel(const int* __restrict__ cnt,
                                                    int* __restrict__ bsum, int N) {
    __shared__ int ts[256];
    int b = blockIdx.x, tid = threadIdx.x;
    int base = b * 1024 + tid * 4;
    int s = 0;
    #pragma unroll
    for (int k = 0; k < 4; ++k) s += (base + k < N) ? cnt[base + k] : 0;
    ts[tid] = s; __syncthreads();
    for (int d = 128; d > 0; d >>= 1) {
        if (tid < d) ts[tid] += ts[tid + d];
        __syncthreads();
    }
    if (tid == 0) bsum[b] = ts[0];
}

__global__ __launch_bounds__(128) void scanB_kernel(const int* __restrict__ bsum,
                                                    int* __restrict__ boff,
                                                    int* __restrict__ off, int NB, int N) {
    __shared__ int ts[128];
    int tid = threadIdx.x;
    int own = (tid < NB) ? bsum[tid] : 0;
    ts[tid] = own; __syncthreads();
    for (int d = 1; d < 128; d <<= 1) {
        int t = (tid >= d) ? ts[tid - d] : 0;
        __syncthreads();
        ts[tid] += t;
        __syncthreads();
    }
    if (tid < NB) boff[tid] = ts[tid] - own;   // exclusive
    if (tid == 127) off[N] = ts[127];          // total = E
}

__global__ __launch_bounds__(256) void scanC_kernel(const int* __restrict__ cnt,
                                                    const int* __restrict__ boff,
                                                    int* __restrict__ off,
                                                    int* __restrict__ cursor, int N) {
    __shared__ int ts[256];
    int b = blockIdx.x, tid = threadIdx.x;
    int base = b * 1024 + tid * 4;
    int v[4]; int s = 0;
    #pragma unroll
    for (int k = 0; k < 4; ++k) { v[k] = (base + k < N) ? cnt[base + k] : 0; s += v[k]; }
    ts[tid] = s; __syncthreads();
    for (int d = 1; d < 256; d <<= 1) {
        int t = (tid >= d) ? ts[tid - d] : 0;
        __syncthreads();
        ts[tid] += t;
        __syncthreads();
    }
    int excl = ts[tid] - s + boff[b];
    #pragma unroll
    for (int k = 0; k < 4; ++k) {
        if (base + k < N) { off[base + k] = excl; cursor[base + k] = excl; excl += v[k]; }
    }
}

// ---- bucket edges by dst: sse[pos] = src, pos = cursor[dst]++ ----
__global__ void bucket_kernel(const int* __restrict__ src, const int* __restrict__ dst,
                              int* __restrict__ cursor, int* __restrict__ sse, int E) {
    int i = blockIdx.x * blockDim.x + threadIdx.x;
    int n = gridDim.x * blockDim.x;
    for (int e = i; e < E; e += n) {
        int d = dst[e];
        int pos = atomicAdd(&cursor[d], 1);
        sse[pos] = src[e];
    }
}

// ---- GEMM1: th = fp16(x @ W1)  [N,128]x[128,64] ----
__global__ __launch_bounds__(256) void gemm1_kernel(
    const float* __restrict__ x, const float* __restrict__ W,
    __half* __restrict__ th, int N) {
    __shared__ float Ws[ID * HD];   // 32 KB
    __shared__ float xs[8][ID];     // 4 KB
    int tid = threadIdx.x;
    for (int i = tid; i < ID * HD; i += 256) Ws[i] = W[i];
    int base = blockIdx.x * 8;
    for (int i = tid; i < 8 * ID; i += 256) {
        int r = i >> 7, c = i & (ID - 1);
        int row = base + r;
        xs[r][c] = (row < N) ? x[(size_t)row * ID + c] : 0.0f;
    }
    __syncthreads();
    int col = tid & 63;
    int rg  = tid >> 6;  // wave id: 0..3, each wave does 2 rows
    float acc0 = 0.f, acc1 = 0.f;
    #pragma unroll 8
    for (int k = 0; k < ID; ++k) {
        float w = Ws[k * HD + col];
        acc0 += xs[rg * 2][k] * w;
        acc1 += xs[rg * 2 + 1][k] * w;
    }
    int r0 = base + rg * 2, r1 = r0 + 1;
    if (r0 < N) th[(size_t)r0 * HD + col] = __float2half(acc0);
    if (r1 < N) th[(size_t)r1 * HD + col] = __float2half(acc1);
}

// ---- pull aggregation: one wave per node, lane = feature channel ----
// a[d] = dinv[d] * sum_{s in N(d)} dinv[s]*th[s] + dinv[d]^2 * th[d]
__global__ __launch_bounds__(256) void pull_kernel(
    const int* __restrict__ off, const int* __restrict__ sse,
    const float* __restrict__ dinv, const __half* __restrict__ th,
    float* __restrict__ a, int N) {
    int lane = threadIdx.x & 63;
    int w = (blockIdx.x * blockDim.x + threadIdx.x) >> 6;
    if (w >= N) return;
    int o0 = off[w], o1 = off[w + 1];
    float acc = 0.f;
    int j = o0;
    for (; j + 3 < o1; j += 4) {
        int s0 = sse[j], s1 = sse[j+1], s2 = sse[j+2], s3 = sse[j+3];
        float n0 = dinv[s0], n1 = dinv[s1], n2 = dinv[s2], n3 = dinv[s3];
        float t0 = __half2float(th[(size_t)s0 * HD + lane]);
        float t1 = __half2float(th[(size_t)s1 * HD + lane]);
        float t2 = __half2float(th[(size_t)s2 * HD + lane]);
        float t3 = __half2float(th[(size_t)s3 * HD + lane]);
        acc += n0 * t0 + n1 * t1 + n2 * t2 + n3 * t3;
    }
    for (; j < o1; ++j) {
        int s = sse[j];
        acc += dinv[s] * __half2float(th[(size_t)s * HD + lane]);
    }
    float dd = dinv[w];
    acc = dd * acc + dd * dd * __half2float(th[(size_t)w * HD + lane]);
    a[(size_t)w * HD + lane] = acc;
}

// ---- GEMM2: th = fp16(relu(a1 + b1) @ W2)  [N,64]x[64,64] ----
__global__ __launch_bounds__(256) void gemm2_kernel(
    const float* __restrict__ ain, const float* __restrict__ W,
    const float* __restrict__ bias, __half* __restrict__ th, int N) {
    __shared__ float Ws[HD * HD];   // 16 KB
    __shared__ float hs[8][HD];     // 2 KB
    int tid = threadIdx.x;
    for (int i = tid; i < HD * HD; i += 256) Ws[i] = W[i];
    int base = blockIdx.x * 8;
    for (int i = tid; i < 8 * HD; i += 256) {
        int r = i >> 6, c = i & 63;
        int row = base + r;
        float v = (row < N) ? ain[(size_t)row * HD + c] + bias[c] : 0.0f;
        hs[r][c] = fmaxf(v, 0.0f);
    }
    __syncthreads();
    int col = tid & 63;
    int rg  = tid >> 6;
    float acc0 = 0.f, acc1 = 0.f;
    #pragma unroll 8
    for (int k = 0; k < HD; ++k) {
        float w = Ws[k * HD + col];
        acc0 += hs[rg * 2][k] * w;
        acc1 += hs[rg * 2 + 1][k] * w;
    }
    int r0 = base + rg * 2, r1 = r0 + 1;
    if (r0 < N) th[(size_t)r0 * HD + col] = __float2half(acc0);
    if (r1 < N) th[(size_t)r1 * HD + col] = __float2half(acc1);
}

// ---- head: out = (a2 + b2) @ Wc + bc   [N,64]x[64,16] ----
__global__ __launch_bounds__(256) void final_kernel(
    const float* __restrict__ ain, const float* __restrict__ b2,
    const float* __restrict__ Wc, const float* __restrict__ bc,
    float* __restrict__ out, int N) {
    __shared__ float Ws[HD * OD];     // 4 KB
    __shared__ float hs[16][HD + 1];  // padded
    int tid = threadIdx.x;
    for (int i = tid; i < HD * OD; i += 256) Ws[i] = Wc[i];
    int base = blockIdx.x * 16;
    for (int i = tid; i < 16 * HD; i += 256) {
        int r = i >> 6, c = i & 63;
        int row = base + r;
        hs[r][c] = (row < N) ? ain[(size_t)row * HD + c] + b2[c] : 0.0f;
    }
    __syncthreads();
    int col = tid & 15, r = tid >> 4;
    int row = base + r;
    if (row < N) {
        float acc = bc[col];
        #pragma unroll
        for (int k = 0; k < HD; ++k)
            acc += hs[r][k] * Ws[k * OD + col];
        out[(size_t)row * OD + col] = acc;
    }
}

extern "C" void kernel_launch(void* const* d_in, const int* in_sizes, int n_in,
                              void* d_out, int out_size, void* d_ws, size_t ws_size,
                              hipStream_t stream) {
    const float* x  = (const float*)d_in[0];
    const int*   ei = (const int*)d_in[1];   // [2,E] flat, int32 per harness
    const float* W1 = (const float*)d_in[2];
    const float* b1 = (const float*)d_in[3];
    const float* W2 = (const float*)d_in[4];
    const float* b2 = (const float*)d_in[5];
    const float* Wc = (const float*)d_in[6];
    const float* bc = (const float*)d_in[7];
    float* out = (float*)d_out;

    int N = in_sizes[0] / ID;   // 100000
    int E = in_sizes[1] / 2;    // 1600000
    const int* src = ei;
    const int* dst = ei + E;

    int Npad = (N + 64) & ~63;          // padded element counts
    char* p = (char*)d_ws;
    int*    cnt    = (int*)p;           p += (size_t)Npad * 4;
    float*  dinv   = (float*)p;         p += (size_t)Npad * 4;
    int*    off    = (int*)p;           p += (size_t)(Npad + 64) * 4;
    int*    cursor = (int*)p;           p += (size_t)Npad * 4;
    int*    bsum   = (int*)p;           p += 128 * 4;
    int*    boff   = (int*)p;           p += 128 * 4;
    int*    sse    = (int*)p;           p += (size_t)E * 4;       // sorted src
    __half* th     = (__half*)p;        p += (size_t)N * HD * 2;  // message table
    float*  a1     = (float*)p;         p += (size_t)N * HD * 4;  // agg out (reused)

    int NB = (N + 1023) / 1024;         // 98 scan blocks

    // ws is re-poisoned each call: cnt must be zeroed; everything else is
    // fully written before being read.
    hipMemsetAsync(cnt, 0, (size_t)N * sizeof(int), stream);

    // CSR build (shared by both layers)
    hist_kernel<<<1024, 256, 0, stream>>>(dst, cnt, E);
    dinv_kernel<<<(N + 255) / 256, 256, 0, stream>>>(cnt, dinv, N);
    scanA_kernel<<<NB, 256, 0, stream>>>(cnt, bsum, N);
    scanB_kernel<<<1, 128, 0, stream>>>(bsum, boff, off, NB, N);
    scanC_kernel<<<NB, 256, 0, stream>>>(cnt, boff, off, cursor, N);
    bucket_kernel<<<1024, 256, 0, stream>>>(src, dst, cursor, sse, E);

    // layer 1
    gemm1_kernel<<<(N + 7) / 8, 256, 0, stream>>>(x, W1, th, N);
    pull_kernel<<<(N * 64 + 255) / 256, 256, 0, stream>>>(off, sse, dinv, th, a1, N);

    // layer 2
    gemm2_kernel<<<(N + 7) / 8, 256, 0, stream>>>(a1, W2, b1, th, N);
    pull_kernel<<<(N * 64 + 255) / 256, 256, 0, stream>>>(off, sse, dinv, th, a1, N);

    // head
    final_kernel<<<(N + 15) / 16, 256, 0, stream>>>(a1, b2, Wc, bc, out, N);
}